// Round 7
// baseline (3085.518 us; speedup 1.0000x reference)
//
#include <hip/hip_runtime.h>
#include <cstdint>
#include <cstddef>

typedef __bf16 bf16;
typedef __bf16 bf16x8 __attribute__((ext_vector_type(8)));
typedef __bf16 bf16x4 __attribute__((ext_vector_type(4)));
typedef float f32x4 __attribute__((ext_vector_type(4)));
typedef unsigned u32x4 __attribute__((ext_vector_type(4)));
typedef unsigned u32x2 __attribute__((ext_vector_type(2)));

#define B_ 64
#define S_ 512
#define E_ 512
#define H_ 1024
#define C_ 20
#define EH 1536   // E+H
#define G4 4096   // 4*H

// ---- workspace layout (bytes) ----
static const size_t OFF_WCAT  = 0;              // bf16 [4096][1536] = 12,582,912
static const size_t OFF_BIAS4 = 12582912;       // f32  [4096]       = 16,384
static const size_t OFF_A0    = 12599296;       // bf16 [64][1024]   = 131,072
static const size_t OFF_A1    = 12730368;       // bf16 [64][1024]   = 131,072
static const size_t OFF_CST   = 12861440;       // f32  [64][1024]   = 262,144
static const size_t OFF_LOSS  = 13123584;       // f32  [64]         = 256
static const size_t OFF_BAR   = 13123840;       // u32  [4][256] wave-flags = 4,096
static const size_t OFF_GX    = 13127936;       // bf16 [TC*64][4096] = TC*524,288
static const size_t STATE_BYTES = OFF_GX - OFF_A0;   // 528,640 (zeroed each call)

__device__ inline float sigmoidf_(float x) { return 1.0f / (1.0f + __expf(-x)); }
__device__ inline float tanh_fast(float x) {
  float ax = fabsf(x);
  float e = __expf(-2.0f * ax);
  float t = (1.0f - e) / (1.0f + e);
  return copysignf(t, x);
}

// ---- zero a0/a1/cst/loss/flags (contiguous state region) ----
__global__ __launch_bounds__(256) void init_misc(uint4* st) {
  const int n = (int)(STATE_BYTES / 16);   // 33,040
  for (int idx = blockIdx.x * 256 + threadIdx.x; idx < n; idx += gridDim.x * 256)
    st[idx] = uint4{0u, 0u, 0u, 0u};
}

// ---- convert gate weights to bf16, rows r = h*4+g (h-major, gate minor) ----
__global__ __launch_bounds__(256) void convert_w(
    const float* __restrict__ Wf, const float* __restrict__ Wi,
    const float* __restrict__ Wc, const float* __restrict__ Wo,
    const float* __restrict__ bfp, const float* __restrict__ bip,
    const float* __restrict__ bcp, const float* __restrict__ bop,
    bf16* __restrict__ Wcat, float* __restrict__ bias4)
{
  const int total = G4 * (EH / 8);   // 786,432 chunks of 8
  for (int idx = blockIdx.x * 256 + threadIdx.x; idx < total; idx += gridDim.x * 256) {
    const int r = idx / 192;
    const int ck = idx - r * 192;
    const int g = r & 3, h = r >> 2;
    const float* W = (g == 0) ? Wf : (g == 1) ? Wi : (g == 2) ? Wc : Wo;
    const float* src = W + (size_t)h * EH + ck * 8;
    const float4 v0 = *(const float4*)src;
    const float4 v1 = *(const float4*)(src + 4);
    bf16x8 o;
    o[0] = (bf16)v0.x; o[1] = (bf16)v0.y; o[2] = (bf16)v0.z; o[3] = (bf16)v0.w;
    o[4] = (bf16)v1.x; o[5] = (bf16)v1.y; o[6] = (bf16)v1.z; o[7] = (bf16)v1.w;
    *(bf16x8*)(Wcat + (size_t)r * EH + ck * 8) = o;
    if (ck == 0) {
      const float* Bp = (g == 0) ? bfp : (g == 1) ? bip : (g == 2) ? bcp : bop;
      bias4[r] = Bp[h];
    }
  }
}

// ---- gx_chunk[ml][r] = sum_k emb[x[m]][k] * Wcat[r][k], K = 512 (x-part) ----
__global__ __launch_bounds__(256) void gemm_gx(
    const int* __restrict__ x, const float* __restrict__ emb,
    const bf16* __restrict__ Wcat, bf16* __restrict__ gx, int t0)
{
  __shared__ char As[16384];
  __shared__ char Bs[16384];
  const int t = threadIdx.x;
  const int lane = t & 63, wid = t >> 6;
  const int wm = wid >> 1, wn = wid & 1;
  const int bm = blockIdx.x >> 5;
  const int bn = blockIdx.x & 31;
  const int m0l = bm * 128, n0 = bn * 128;
  f32x4 acc[4][4] = {};
  const int srow = t >> 3, sc16 = t & 7;
  for (int k0 = 0; k0 < E_; k0 += 64) {
    __syncthreads();
    #pragma unroll
    for (int i = 0; i < 4; ++i) {
      const int row = i * 32 + srow;
      const int cs = sc16 ^ (row & 7);     // pre-swizzled source chunk
      const int m = t0 * 64 + m0l + row;
      const int tok = x[(m & 63) * S_ + (m >> 6)];
      const float* srcA = emb + (size_t)tok * E_ + k0 + cs * 8;
      const float4 a0v = *(const float4*)srcA;
      const float4 a1v = *(const float4*)(srcA + 4);
      bf16x8 oa;
      oa[0] = (bf16)a0v.x; oa[1] = (bf16)a0v.y; oa[2] = (bf16)a0v.z; oa[3] = (bf16)a0v.w;
      oa[4] = (bf16)a1v.x; oa[5] = (bf16)a1v.y; oa[6] = (bf16)a1v.z; oa[7] = (bf16)a1v.w;
      *(bf16x8*)(As + row * 128 + sc16 * 16) = oa;
      const uint4 vb = *(const uint4*)(Wcat + (size_t)(n0 + row) * EH + k0 + cs * 8);
      *(uint4*)(Bs + row * 128 + sc16 * 16) = vb;
    }
    __syncthreads();
    #pragma unroll
    for (int ks = 0; ks < 64; ks += 32) {
      const int kb = (ks + ((lane >> 4) * 8)) * 2;
      bf16x8 af[4], bfr[4];
      #pragma unroll
      for (int mt = 0; mt < 4; ++mt) {
        const int ra = wm * 64 + mt * 16 + (lane & 15);
        af[mt] = *(const bf16x8*)(As + ra * 128 + (kb ^ ((ra & 7) << 4)));
      }
      #pragma unroll
      for (int nt = 0; nt < 4; ++nt) {
        const int rb = wn * 64 + nt * 16 + (lane & 15);
        bfr[nt] = *(const bf16x8*)(Bs + rb * 128 + (kb ^ ((rb & 7) << 4)));
      }
      #pragma unroll
      for (int mt = 0; mt < 4; ++mt)
        #pragma unroll
        for (int nt = 0; nt < 4; ++nt)
          acc[mt][nt] = __builtin_amdgcn_mfma_f32_16x16x32_bf16(af[mt], bfr[nt], acc[mt][nt], 0, 0, 0);
    }
  }
  const int cb = (lane >> 4) * 4;
  #pragma unroll
  for (int mt = 0; mt < 4; ++mt) {
    #pragma unroll
    for (int r = 0; r < 4; ++r) {
      const int mrow = m0l + wm * 64 + mt * 16 + cb + r;   // chunk-local row
      bf16* dst = gx + (size_t)mrow * G4 + n0 + wn * 64 + (lane & 15);
      #pragma unroll
      for (int nt = 0; nt < 4; ++nt)
        dst[nt * 16] = (bf16)acc[mt][nt][r];
    }
  }
}

// ---- persistent LSTM recurrence over steps [t0, t0+tc) ----
// 256 WGs = 4 batch-groups (16 batches) x 64 hidden-slice WGs (16 h each).
// R7 protocol: per-(WG,wave) flags (256/group). Producer wave: packed 8B
// sc0sc1 data stores -> wave-local vmcnt(0) drain -> lane0 flag store
// (value step+1). Consumer lane polls exactly the 8 flags covering its 8
// A-fragments (32B/iter) and issues each 16B payload load AS SOON AS its
// producer's flag lands (divergent early issue) -> straggler wait overlaps
// payload round-trips. Data read once; poll traffic O(flags). No fences,
// no tags; freshness: flag observed => producer wave drained => later-
// serviced load fresh. Depth-2 ring (a0/a1) safety as before.
__global__ __launch_bounds__(256, 1) void lstm_rec(
    const bf16* __restrict__ Wcat, const float* __restrict__ bias4,
    const bf16* __restrict__ gx, bf16* __restrict__ a0,
    bf16* __restrict__ a1, float* __restrict__ cstg,
    unsigned* __restrict__ bar, int t0, int tc)
{
  __shared__ __align__(16) float accs[2][4][16][68];   // parity double-buffer
  const int t = threadIdx.x;
  const int lane = t & 63;
  const int w = t >> 6;                     // wave id = K-quarter
  const int bid = blockIdx.x;
  const int grp = bid & 3;                  // batch group (16 batches)
  const int hwg = bid >> 2;                 // 0..63 hidden slice
  const int h0 = hwg * 16;
  const int l15 = lane & 15;
  const int ksub = lane >> 4;               // 0..3
  const int kq8 = ksub * 8;

  // --- preload W B-fragments: 64 gate rows x my K-quarter (256 cols) ---
  bf16x8 wf[32];                            // static-indexed -> regs/AGPRs
  {
    const bf16* wbase = Wcat + (size_t)(h0 * 4 + l15) * EH + 512 + w * 256 + kq8;
    #pragma unroll
    for (int nt = 0; nt < 4; ++nt)
      #pragma unroll
      for (int i = 0; i < 8; ++i)
        wf[nt * 8 + i] = *(const bf16x8*)(wbase + (size_t)nt * 16 * EH + i * 32);
  }
  const int j   = t & 15;                   // hidden unit within slice
  const int blb = t >> 4;                   // batch within group
  const float4 bias = *(const float4*)(bias4 + (h0 + j) * 4);
  const int bg0 = grp * 16 + blb;
  float cst = cstg[(size_t)bg0 * H_ + h0 + j];
  unsigned* gflags = bar + grp * 256;       // [64 WG][4 wave]
  // consumer: piece i (i=0..7) -> producer WG 16w + 2i + (ksub>>1), wave l15>>2
  unsigned* fbase = gflags + (16 * w + (ksub >> 1)) * 4 + (l15 >> 2);
  // payload base: batch (grp*16+l15), k = w*256 + kq8 + i*32
  const size_t pbase = (size_t)(grp * 16 + l15) * H_ + w * 256 + kq8;
  // producer: store 8B at a[bg0][h0 + j] for j%4==0; flag gflags[hwg*4 + w]
  unsigned* myflag = gflags + hwg * 4 + w;

  for (int s = 0; s < tc; ++s) {
    const int step = t0 + s;
    const unsigned tgt = (unsigned)step;    // need producer flag >= step
    const bf16* aprev = (step & 1) ? a1 : a0;
    bf16* anext = (step & 1) ? a0 : a1;
    // gx for this step (plain cached load, issued before the poll)
    const bf16x4 g0 = *(const bf16x4*)(gx + (size_t)s * (B_ * G4) + (size_t)bg0 * G4 + (h0 + j) * 4);

    // --- poll 8 flags, early-issue each payload piece on its flag ---
    u32x4 pay[8];
    unsigned fv[8];
    unsigned need = 0xffu;
    while (need) {
      #pragma unroll
      for (int i = 0; i < 8; ++i) {
        if (need & (1u << i)) {
          asm volatile("global_load_dword %0, %1, off sc0 sc1"
                       : "=v"(fv[i]) : "v"(fbase + 8 * i) : "memory");
        }
      }
      asm volatile("s_waitcnt vmcnt(0)" ::: "memory");
      __builtin_amdgcn_sched_barrier(0);
      #pragma unroll
      for (int i = 0; i < 8; ++i) {
        if ((need & (1u << i)) && fv[i] >= tgt) {
          asm volatile("global_load_dwordx4 %0, %1, off sc0 sc1"
                       : "=v"(pay[i]) : "v"(aprev + pbase + i * 32) : "memory");
          need &= ~(1u << i);
        }
      }
    }
    asm volatile("s_waitcnt vmcnt(0)" ::: "memory");
    __builtin_amdgcn_sched_barrier(0);

    // --- MFMA over my K-quarter ---
    f32x4 pacc[4] = {};
    #pragma unroll
    for (int i = 0; i < 8; ++i) {
      const bf16x8 a8 = __builtin_bit_cast(bf16x8, pay[i]);
      #pragma unroll
      for (int nt = 0; nt < 4; ++nt)
        pacc[nt] = __builtin_amdgcn_mfma_f32_16x16x32_bf16(a8, wf[nt * 8 + i], pacc[nt], 0, 0, 0);
    }
    // --- cross-wave K-reduction via parity LDS (single barrier) ---
    const int par = step & 1;
    {
      const int m0 = ksub * 4;
      #pragma unroll
      for (int nt = 0; nt < 4; ++nt)
        #pragma unroll
        for (int r = 0; r < 4; ++r)
          accs[par][w][m0 + r][nt * 16 + l15] = pacc[nt][r];
    }
    __syncthreads();
    const float4 q0 = *(const float4*)&accs[par][0][blb][j * 4];
    const float4 q1 = *(const float4*)&accs[par][1][blb][j * 4];
    const float4 q2 = *(const float4*)&accs[par][2][blb][j * 4];
    const float4 q3 = *(const float4*)&accs[par][3][blb][j * 4];
    float hv;
    {
      const float pf = q0.x + q1.x + q2.x + q3.x + (float)g0[0] + bias.x;
      const float pi = q0.y + q1.y + q2.y + q3.y + (float)g0[1] + bias.y;
      const float pc = q0.z + q1.z + q2.z + q3.z + (float)g0[2] + bias.z;
      const float po = q0.w + q1.w + q2.w + q3.w + (float)g0[3] + bias.w;
      const float fg = sigmoidf_(pf), ig = sigmoidf_(pi), og = sigmoidf_(po);
      cst = fg * cst + ig * tanh_fast(pc);
      hv = tanh_fast(cst) * og;
    }
    // --- publish: pack 4 bf16 per 8B, sc0sc1 store; wave drain; wave flag ---
    {
      const unsigned me = (unsigned)__builtin_bit_cast(unsigned short, (bf16)hv);
      const unsigned pr  = me | (__shfl_down(me, 1) << 16);
      const unsigned pr2 = __shfl_down(pr, 2);
      if ((j & 3) == 0) {
        u32x2 pv; pv.x = pr; pv.y = pr2;
        asm volatile("global_store_dwordx2 %0, %1, off sc0 sc1"
                     :: "v"(anext + (size_t)bg0 * H_ + h0 + j), "v"(pv) : "memory");
      }
    }
    asm volatile("s_waitcnt vmcnt(0)" ::: "memory");   // wave-local drain
    __builtin_amdgcn_sched_barrier(0);
    if (lane == 0) {
      const unsigned nf = (unsigned)(step + 1);
      asm volatile("global_store_dword %0, %1, off sc0 sc1"
                   :: "v"(myflag), "v"(nf) : "memory");
    }
  }
  cstg[(size_t)bg0 * H_ + h0 + j] = cst;
}

// ---- logits + per-batch loss ----
__global__ __launch_bounds__(256) void logits_loss(
    const bf16* __restrict__ afin, const float* __restrict__ Wv,
    const float* __restrict__ bv, const int* __restrict__ label,
    float* __restrict__ lossa)
{
  const int b = blockIdx.x;
  const int t = threadIdx.x;
  const int lane = t & 63, wid = t >> 6;
  const bf16x4 a4 = *(const bf16x4*)(afin + (size_t)b * H_ + t * 4);
  const float av0 = (float)a4[0], av1 = (float)a4[1], av2 = (float)a4[2], av3 = (float)a4[3];
  float part[C_];
  #pragma unroll
  for (int c = 0; c < C_; ++c) {
    const float4 w = *(const float4*)(Wv + (size_t)c * H_ + t * 4);
    part[c] = av0 * w.x + av1 * w.y + av2 * w.z + av3 * w.w;
  }
  #pragma unroll
  for (int off = 32; off > 0; off >>= 1) {
    #pragma unroll
    for (int c = 0; c < C_; ++c) part[c] += __shfl_down(part[c], off);
  }
  __shared__ float red[4][C_];
  __shared__ float lg[C_];
  if (lane == 0) {
    #pragma unroll
    for (int c = 0; c < C_; ++c) red[wid][c] = part[c];
  }
  __syncthreads();
  if (t < C_) lg[t] = red[0][t] + red[1][t] + red[2][t] + red[3][t] + bv[t];
  __syncthreads();
  if (t == 0) {
    float m = lg[0];
    for (int c = 1; c < C_; ++c) m = fmaxf(m, lg[c]);
    float se = 0.0f;
    for (int c = 0; c < C_; ++c) se += __expf(lg[c] - m);
    const float lse = logf(se) + m;
    lossa[b] = lse - lg[label[b]];
  }
}

__global__ __launch_bounds__(64) void loss_mean(const float* __restrict__ lossa,
                                                float* __restrict__ out) {
  const int t = threadIdx.x;
  float v = lossa[t];
  #pragma unroll
  for (int off = 32; off > 0; off >>= 1) v += __shfl_down(v, off);
  if (t == 0) out[0] = v * (1.0f / 64.0f);
}

extern "C" void kernel_launch(void* const* d_in, const int* in_sizes, int n_in,
                              void* d_out, int out_size, void* d_ws, size_t ws_size,
                              hipStream_t stream) {
  const int*   x     = (const int*)d_in[0];
  const int*   label = (const int*)d_in[1];
  const float* emb   = (const float*)d_in[2];
  const float* Wf    = (const float*)d_in[3];
  const float* bfp   = (const float*)d_in[4];
  const float* Wi    = (const float*)d_in[5];
  const float* bip   = (const float*)d_in[6];
  const float* Wc    = (const float*)d_in[7];
  const float* bcp   = (const float*)d_in[8];
  const float* Wo    = (const float*)d_in[9];
  const float* bop   = (const float*)d_in[10];
  const float* Wv    = (const float*)d_in[11];
  const float* bv    = (const float*)d_in[12];
  (void)in_sizes; (void)n_in; (void)out_size;

  // Pick the largest time-chunk TC whose gx buffer fits the workspace.
  int TC = 0;
  const size_t avail = (ws_size > OFF_GX) ? (ws_size - OFF_GX) : 0;
  const int cands[7] = {512, 256, 128, 64, 32, 16, 8};
  for (int i = 0; i < 7; ++i) {
    if ((size_t)cands[i] * 524288 <= avail) { TC = cands[i]; break; }
  }
  if (TC == 0) return;   // ws < ~17.6 MB — cannot run this design

  char* ws = (char*)d_ws;
  bf16*     Wcat  = (bf16*)(ws + OFF_WCAT);
  float*    bias4 = (float*)(ws + OFF_BIAS4);
  bf16*     a0    = (bf16*)(ws + OFF_A0);
  bf16*     a1    = (bf16*)(ws + OFF_A1);
  float*    cstg  = (float*)(ws + OFF_CST);
  float*    lossa = (float*)(ws + OFF_LOSS);
  unsigned* bar   = (unsigned*)(ws + OFF_BAR);
  bf16*     gx    = (bf16*)(ws + OFF_GX);

  init_misc<<<64, 256, 0, stream>>>((uint4*)(ws + OFF_A0));
  convert_w<<<1024, 256, 0, stream>>>(Wf, Wi, Wc, Wo, bfp, bip, bcp, bop, Wcat, bias4);
  const int nchunks = S_ / TC;
  for (int c = 0; c < nchunks; ++c) {
    const int t0 = c * TC;
    gemm_gx<<<(TC / 2) * 32, 256, 0, stream>>>(x, emb, Wcat, gx, t0);
    lstm_rec<<<256, 256, 0, stream>>>(Wcat, bias4, gx, a0, a1, cstg, bar, t0, TC);
  }
  // final state = out(511) in buffer (511+1)&1 = 0 -> a0
  logits_loss<<<64, 256, 0, stream>>>(a0, Wv, bv, label, lossa);
  loss_mean<<<1, 64, 0, stream>>>(lossa, (float*)d_out);
}

// Round 8
// 2869.670 us; speedup vs baseline: 1.0752x; 1.0752x over previous
//
#include <hip/hip_runtime.h>
#include <cstdint>
#include <cstddef>

typedef __bf16 bf16;
typedef __bf16 bf16x8 __attribute__((ext_vector_type(8)));
typedef __bf16 bf16x4 __attribute__((ext_vector_type(4)));
typedef float f32x4 __attribute__((ext_vector_type(4)));
typedef unsigned u32x4 __attribute__((ext_vector_type(4)));

#define B_ 64
#define S_ 512
#define E_ 512
#define H_ 1024
#define C_ 20
#define EH 1536   // E+H
#define G4 4096   // 4*H

// ---- workspace layout (bytes) ----
static const size_t OFF_WCAT  = 0;              // bf16 [4096][1536] = 12,582,912
static const size_t OFF_BIAS4 = 12582912;       // f32  [4096]       = 16,384
static const size_t OFF_A0    = 12599296;       // bf16 [64][1024]   = 131,072
static const size_t OFF_A1    = 12730368;       // bf16 [64][1024]   = 131,072
static const size_t OFF_CST   = 12861440;       // f32  [64][1024]   = 262,144
static const size_t OFF_LOSS  = 13123584;       // f32  [64]         = 256
static const size_t OFF_BAR   = 13123840;       // u32  [4][64][4] wave-flags = 4,096
static const size_t OFF_GX    = 13127936;       // bf16 [TC*64][4096] = TC*524,288
static const size_t STATE_BYTES = OFF_GX - OFF_A0;   // 528,640 (zeroed each call)

__device__ inline float sigmoidf_(float x) { return 1.0f / (1.0f + __expf(-x)); }
__device__ inline float tanh_fast(float x) {
  float ax = fabsf(x);
  float e = __expf(-2.0f * ax);
  float t = (1.0f - e) / (1.0f + e);
  return copysignf(t, x);
}

// ---- zero a0/a1/cst/loss/flags (contiguous state region) ----
__global__ __launch_bounds__(256) void init_misc(uint4* st) {
  const int n = (int)(STATE_BYTES / 16);   // 33,040
  for (int idx = blockIdx.x * 256 + threadIdx.x; idx < n; idx += gridDim.x * 256)
    st[idx] = uint4{0u, 0u, 0u, 0u};
}

// ---- convert gate weights to bf16, rows r = h*4+g (h-major, gate minor) ----
__global__ __launch_bounds__(256) void convert_w(
    const float* __restrict__ Wf, const float* __restrict__ Wi,
    const float* __restrict__ Wc, const float* __restrict__ Wo,
    const float* __restrict__ bfp, const float* __restrict__ bip,
    const float* __restrict__ bcp, const float* __restrict__ bop,
    bf16* __restrict__ Wcat, float* __restrict__ bias4)
{
  const int total = G4 * (EH / 8);   // 786,432 chunks of 8
  for (int idx = blockIdx.x * 256 + threadIdx.x; idx < total; idx += gridDim.x * 256) {
    const int r = idx / 192;
    const int ck = idx - r * 192;
    const int g = r & 3, h = r >> 2;
    const float* W = (g == 0) ? Wf : (g == 1) ? Wi : (g == 2) ? Wc : Wo;
    const float* src = W + (size_t)h * EH + ck * 8;
    const float4 v0 = *(const float4*)src;
    const float4 v1 = *(const float4*)(src + 4);
    bf16x8 o;
    o[0] = (bf16)v0.x; o[1] = (bf16)v0.y; o[2] = (bf16)v0.z; o[3] = (bf16)v0.w;
    o[4] = (bf16)v1.x; o[5] = (bf16)v1.y; o[6] = (bf16)v1.z; o[7] = (bf16)v1.w;
    *(bf16x8*)(Wcat + (size_t)r * EH + ck * 8) = o;
    if (ck == 0) {
      const float* Bp = (g == 0) ? bfp : (g == 1) ? bip : (g == 2) ? bcp : bop;
      bias4[r] = Bp[h];
    }
  }
}

// ---- gx_chunk[ml][r] = sum_k emb[x[m]][k] * Wcat[r][k], K = 512 (x-part) ----
__global__ __launch_bounds__(256) void gemm_gx(
    const int* __restrict__ x, const float* __restrict__ emb,
    const bf16* __restrict__ Wcat, bf16* __restrict__ gx, int t0)
{
  __shared__ char As[16384];
  __shared__ char Bs[16384];
  const int t = threadIdx.x;
  const int lane = t & 63, wid = t >> 6;
  const int wm = wid >> 1, wn = wid & 1;
  const int bm = blockIdx.x >> 5;
  const int bn = blockIdx.x & 31;
  const int m0l = bm * 128, n0 = bn * 128;
  f32x4 acc[4][4] = {};
  const int srow = t >> 3, sc16 = t & 7;
  for (int k0 = 0; k0 < E_; k0 += 64) {
    __syncthreads();
    #pragma unroll
    for (int i = 0; i < 4; ++i) {
      const int row = i * 32 + srow;
      const int cs = sc16 ^ (row & 7);     // pre-swizzled source chunk
      const int m = t0 * 64 + m0l + row;
      const int tok = x[(m & 63) * S_ + (m >> 6)];
      const float* srcA = emb + (size_t)tok * E_ + k0 + cs * 8;
      const float4 a0v = *(const float4*)srcA;
      const float4 a1v = *(const float4*)(srcA + 4);
      bf16x8 oa;
      oa[0] = (bf16)a0v.x; oa[1] = (bf16)a0v.y; oa[2] = (bf16)a0v.z; oa[3] = (bf16)a0v.w;
      oa[4] = (bf16)a1v.x; oa[5] = (bf16)a1v.y; oa[6] = (bf16)a1v.z; oa[7] = (bf16)a1v.w;
      *(bf16x8*)(As + row * 128 + sc16 * 16) = oa;
      const uint4 vb = *(const uint4*)(Wcat + (size_t)(n0 + row) * EH + k0 + cs * 8);
      *(uint4*)(Bs + row * 128 + sc16 * 16) = vb;
    }
    __syncthreads();
    #pragma unroll
    for (int ks = 0; ks < 64; ks += 32) {
      const int kb = (ks + ((lane >> 4) * 8)) * 2;
      bf16x8 af[4], bfr[4];
      #pragma unroll
      for (int mt = 0; mt < 4; ++mt) {
        const int ra = wm * 64 + mt * 16 + (lane & 15);
        af[mt] = *(const bf16x8*)(As + ra * 128 + (kb ^ ((ra & 7) << 4)));
      }
      #pragma unroll
      for (int nt = 0; nt < 4; ++nt) {
        const int rb = wn * 64 + nt * 16 + (lane & 15);
        bfr[nt] = *(const bf16x8*)(Bs + rb * 128 + (kb ^ ((rb & 7) << 4)));
      }
      #pragma unroll
      for (int mt = 0; mt < 4; ++mt)
        #pragma unroll
        for (int nt = 0; nt < 4; ++nt)
          acc[mt][nt] = __builtin_amdgcn_mfma_f32_16x16x32_bf16(af[mt], bfr[nt], acc[mt][nt], 0, 0, 0);
    }
  }
  const int cb = (lane >> 4) * 4;
  #pragma unroll
  for (int mt = 0; mt < 4; ++mt) {
    #pragma unroll
    for (int r = 0; r < 4; ++r) {
      const int mrow = m0l + wm * 64 + mt * 16 + cb + r;   // chunk-local row
      bf16* dst = gx + (size_t)mrow * G4 + n0 + wn * 64 + (lane & 15);
      #pragma unroll
      for (int nt = 0; nt < 4; ++nt)
        dst[nt * 16] = (bf16)acc[mt][nt][r];
    }
  }
}

// ---- persistent LSTM recurrence over steps [t0, t0+tc) ----
// 256 WGs = 4 batch-groups (16 batches) x 64 hidden-slice WGs (16 h each).
// R8 = R5 protocol + contention surgery:
//  * per-(WG,wave) flags [64][4]/group; producer wave: 16B oct-packed sc0sc1
//    data stores -> wave-local vmcnt(0) -> lane0 flag store (no WG barrier).
//  * ONLY wave 0 polls: lane p checks producer WG p's 4 wave-flags with one
//    dwordx4 (64 lanes cover all 64 WGs; __all reconverges) -> ~16x less
//    flag-line traffic at the MALL. Waves 1-3 spin on an LDS 'go' word.
//  * payload read exactly once (8 x 16B sc0sc1 per lane) after go.
// Ring-depth-2 safety: flag >= t+2 transitively implies all h(t) payload
// reads retired (reads precede each WG's own publish), so overwrite is safe.
__global__ __launch_bounds__(256, 1) void lstm_rec(
    const bf16* __restrict__ Wcat, const float* __restrict__ bias4,
    const bf16* __restrict__ gx, bf16* __restrict__ a0,
    bf16* __restrict__ a1, float* __restrict__ cstg,
    unsigned* __restrict__ bar, int t0, int tc)
{
  __shared__ __align__(16) float accs[2][4][16][68];   // parity double-buffer
  __shared__ int go_lds;
  const int t = threadIdx.x;
  const int lane = t & 63;
  const int w = t >> 6;                     // wave id = K-quarter
  const int bid = blockIdx.x;
  const int grp = bid & 3;                  // batch group (16 batches)
  const int hwg = bid >> 2;                 // 0..63 hidden slice
  const int h0 = hwg * 16;
  const int l15 = lane & 15;
  const int ksub = lane >> 4;               // 0..3
  const int kq8 = ksub * 8;

  // --- preload W B-fragments: 64 gate rows x my K-quarter (256 cols) ---
  bf16x8 wf[32];                            // static-indexed -> regs/AGPRs
  {
    const bf16* wbase = Wcat + (size_t)(h0 * 4 + l15) * EH + 512 + w * 256 + kq8;
    #pragma unroll
    for (int nt = 0; nt < 4; ++nt)
      #pragma unroll
      for (int i = 0; i < 8; ++i)
        wf[nt * 8 + i] = *(const bf16x8*)(wbase + (size_t)nt * 16 * EH + i * 32);
  }
  const int j   = t & 15;                   // hidden unit within slice
  const int blb = t >> 4;                   // batch within group
  const float4 bias = *(const float4*)(bias4 + (h0 + j) * 4);
  const int bg0 = grp * 16 + blb;
  float cst = cstg[(size_t)bg0 * H_ + h0 + j];
  unsigned* gflags = bar + grp * 256;       // [64 WG][4 wave]
  unsigned* myflag = gflags + hwg * 4 + w;  // this wave's producer flag
  const unsigned* pollp = gflags + lane * 4; // wave0 lane p -> WG p's 4 flags
  // payload base: batch (grp*16+l15), k = w*256 + kq8 + i*32
  const size_t pbase = (size_t)(grp * 16 + l15) * H_ + w * 256 + kq8;

  if (t == 0)
    __hip_atomic_store(&go_lds, t0 - 1, __ATOMIC_RELAXED, __HIP_MEMORY_SCOPE_WORKGROUP);
  __syncthreads();

  for (int s = 0; s < tc; ++s) {
    const int step = t0 + s;
    const bf16* aprev = (step & 1) ? a1 : a0;
    bf16* anext = (step & 1) ? a0 : a1;
    // gx for this step (plain cached load; overlaps the wait)
    const bf16x4 g0 = *(const bf16x4*)(gx + (size_t)s * (B_ * G4) + (size_t)bg0 * G4 + (h0 + j) * 4);

    // ---- readiness wait ----
    if (w == 0) {
      const unsigned tgt = (unsigned)step;
      u32x4 fq;
      for (;;) {
        asm volatile("global_load_dwordx4 %0, %1, off sc0 sc1"
                     : "=v"(fq) : "v"(pollp) : "memory");
        asm volatile("s_waitcnt vmcnt(0)" ::: "memory");
        __builtin_amdgcn_sched_barrier(0);
        const int ok = (fq.x >= tgt) && (fq.y >= tgt) && (fq.z >= tgt) && (fq.w >= tgt);
        if (__all(ok)) break;
      }
      if (lane == 0)
        __hip_atomic_store(&go_lds, step, __ATOMIC_RELAXED, __HIP_MEMORY_SCOPE_WORKGROUP);
    } else {
      while (__hip_atomic_load(&go_lds, __ATOMIC_RELAXED, __HIP_MEMORY_SCOPE_WORKGROUP) < step) {}
    }
    __builtin_amdgcn_sched_barrier(0);

    // ---- payload: 8 x 16B coherent loads, read exactly once ----
    u32x4 pay[8];
    #pragma unroll
    for (int i = 0; i < 8; ++i)
      asm volatile("global_load_dwordx4 %0, %1, off sc0 sc1"
                   : "=v"(pay[i]) : "v"(aprev + pbase + i * 32) : "memory");
    asm volatile("s_waitcnt vmcnt(0)" ::: "memory");
    __builtin_amdgcn_sched_barrier(0);

    // ---- MFMA over my K-quarter ----
    f32x4 pacc[4] = {};
    #pragma unroll
    for (int i = 0; i < 8; ++i) {
      const bf16x8 a8 = __builtin_bit_cast(bf16x8, pay[i]);
      #pragma unroll
      for (int nt = 0; nt < 4; ++nt)
        pacc[nt] = __builtin_amdgcn_mfma_f32_16x16x32_bf16(a8, wf[nt * 8 + i], pacc[nt], 0, 0, 0);
    }
    // ---- cross-wave K-reduction via parity LDS (single barrier) ----
    const int par = step & 1;
    {
      const int m0 = ksub * 4;
      #pragma unroll
      for (int nt = 0; nt < 4; ++nt)
        #pragma unroll
        for (int r = 0; r < 4; ++r)
          accs[par][w][m0 + r][nt * 16 + l15] = pacc[nt][r];
    }
    __syncthreads();
    const float4 q0 = *(const float4*)&accs[par][0][blb][j * 4];
    const float4 q1 = *(const float4*)&accs[par][1][blb][j * 4];
    const float4 q2 = *(const float4*)&accs[par][2][blb][j * 4];
    const float4 q3 = *(const float4*)&accs[par][3][blb][j * 4];
    float hv;
    {
      const float pf = q0.x + q1.x + q2.x + q3.x + (float)g0[0] + bias.x;
      const float pi = q0.y + q1.y + q2.y + q3.y + (float)g0[1] + bias.y;
      const float pc = q0.z + q1.z + q2.z + q3.z + (float)g0[2] + bias.z;
      const float po = q0.w + q1.w + q2.w + q3.w + (float)g0[3] + bias.w;
      const float fg = sigmoidf_(pf), ig = sigmoidf_(pi), og = sigmoidf_(po);
      cst = fg * cst + ig * tanh_fast(pc);
      hv = tanh_fast(cst) * og;
    }
    // ---- publish: oct-pack 8 bf16 -> one 16B sc0sc1 store (j%8==0 lanes) ----
    {
      const unsigned me  = (unsigned)__builtin_bit_cast(unsigned short, (bf16)hv);
      const unsigned pr  = me | (__shfl_down(me, 1) << 16);
      const unsigned pr2 = __shfl_down(pr, 2);
      const unsigned pr4 = __shfl_down(pr, 4);
      const unsigned pr24 = __shfl_down(pr2, 4);
      if ((j & 7) == 0) {
        u32x4 o; o.x = pr; o.y = pr2; o.z = pr4; o.w = pr24;
        asm volatile("global_store_dwordx4 %0, %1, off sc0 sc1"
                     :: "v"(anext + (size_t)bg0 * H_ + h0 + j), "v"(o) : "memory");
      }
    }
    asm volatile("s_waitcnt vmcnt(0)" ::: "memory");   // wave-local drain
    __builtin_amdgcn_sched_barrier(0);
    if (lane == 0) {
      const unsigned nf = (unsigned)(step + 1);
      asm volatile("global_store_dword %0, %1, off sc0 sc1"
                   :: "v"(myflag), "v"(nf) : "memory");
    }
  }
  cstg[(size_t)bg0 * H_ + h0 + j] = cst;
}

// ---- logits + per-batch loss ----
__global__ __launch_bounds__(256) void logits_loss(
    const bf16* __restrict__ afin, const float* __restrict__ Wv,
    const float* __restrict__ bv, const int* __restrict__ label,
    float* __restrict__ lossa)
{
  const int b = blockIdx.x;
  const int t = threadIdx.x;
  const int lane = t & 63, wid = t >> 6;
  const bf16x4 a4 = *(const bf16x4*)(afin + (size_t)b * H_ + t * 4);
  const float av0 = (float)a4[0], av1 = (float)a4[1], av2 = (float)a4[2], av3 = (float)a4[3];
  float part[C_];
  #pragma unroll
  for (int c = 0; c < C_; ++c) {
    const float4 w = *(const float4*)(Wv + (size_t)c * H_ + t * 4);
    part[c] = av0 * w.x + av1 * w.y + av2 * w.z + av3 * w.w;
  }
  #pragma unroll
  for (int off = 32; off > 0; off >>= 1) {
    #pragma unroll
    for (int c = 0; c < C_; ++c) part[c] += __shfl_down(part[c], off);
  }
  __shared__ float red[4][C_];
  __shared__ float lg[C_];
  if (lane == 0) {
    #pragma unroll
    for (int c = 0; c < C_; ++c) red[wid][c] = part[c];
  }
  __syncthreads();
  if (t < C_) lg[t] = red[0][t] + red[1][t] + red[2][t] + red[3][t] + bv[t];
  __syncthreads();
  if (t == 0) {
    float m = lg[0];
    for (int c = 1; c < C_; ++c) m = fmaxf(m, lg[c]);
    float se = 0.0f;
    for (int c = 0; c < C_; ++c) se += __expf(lg[c] - m);
    const float lse = logf(se) + m;
    lossa[b] = lse - lg[label[b]];
  }
}

__global__ __launch_bounds__(64) void loss_mean(const float* __restrict__ lossa,
                                                float* __restrict__ out) {
  const int t = threadIdx.x;
  float v = lossa[t];
  #pragma unroll
  for (int off = 32; off > 0; off >>= 1) v += __shfl_down(v, off);
  if (t == 0) out[0] = v * (1.0f / 64.0f);
}

extern "C" void kernel_launch(void* const* d_in, const int* in_sizes, int n_in,
                              void* d_out, int out_size, void* d_ws, size_t ws_size,
                              hipStream_t stream) {
  const int*   x     = (const int*)d_in[0];
  const int*   label = (const int*)d_in[1];
  const float* emb   = (const float*)d_in[2];
  const float* Wf    = (const float*)d_in[3];
  const float* bfp   = (const float*)d_in[4];
  const float* Wi    = (const float*)d_in[5];
  const float* bip   = (const float*)d_in[6];
  const float* Wc    = (const float*)d_in[7];
  const float* bcp   = (const float*)d_in[8];
  const float* Wo    = (const float*)d_in[9];
  const float* bop   = (const float*)d_in[10];
  const float* Wv    = (const float*)d_in[11];
  const float* bv    = (const float*)d_in[12];
  (void)in_sizes; (void)n_in; (void)out_size;

  // Pick the largest time-chunk TC whose gx buffer fits the workspace.
  int TC = 0;
  const size_t avail = (ws_size > OFF_GX) ? (ws_size - OFF_GX) : 0;
  const int cands[7] = {512, 256, 128, 64, 32, 16, 8};
  for (int i = 0; i < 7; ++i) {
    if ((size_t)cands[i] * 524288 <= avail) { TC = cands[i]; break; }
  }
  if (TC == 0) return;   // ws < ~17.6 MB — cannot run this design

  char* ws = (char*)d_ws;
  bf16*     Wcat  = (bf16*)(ws + OFF_WCAT);
  float*    bias4 = (float*)(ws + OFF_BIAS4);
  bf16*     a0    = (bf16*)(ws + OFF_A0);
  bf16*     a1    = (bf16*)(ws + OFF_A1);
  float*    cstg  = (float*)(ws + OFF_CST);
  float*    lossa = (float*)(ws + OFF_LOSS);
  unsigned* bar   = (unsigned*)(ws + OFF_BAR);
  bf16*     gx    = (bf16*)(ws + OFF_GX);

  init_misc<<<64, 256, 0, stream>>>((uint4*)(ws + OFF_A0));
  convert_w<<<1024, 256, 0, stream>>>(Wf, Wi, Wc, Wo, bfp, bip, bcp, bop, Wcat, bias4);
  const int nchunks = S_ / TC;
  for (int c = 0; c < nchunks; ++c) {
    const int t0 = c * TC;
    gemm_gx<<<(TC / 2) * 32, 256, 0, stream>>>(x, emb, Wcat, gx, t0);
    lstm_rec<<<256, 256, 0, stream>>>(Wcat, bias4, gx, a0, a1, cstg, bar, t0, TC);
  }
  // final state = out(511) in buffer (511+1)&1 = 0 -> a0
  logits_loss<<<64, 256, 0, stream>>>(a0, Wv, bv, label, lossa);
  loss_mean<<<1, 64, 0, stream>>>(lossa, (float*)d_out);
}

// Round 9
// 2542.196 us; speedup vs baseline: 1.2137x; 1.1288x over previous
//
#include <hip/hip_runtime.h>
#include <cstdint>
#include <cstddef>

typedef __bf16 bf16;
typedef __bf16 bf16x8 __attribute__((ext_vector_type(8)));
typedef __bf16 bf16x4 __attribute__((ext_vector_type(4)));
typedef float f32x4 __attribute__((ext_vector_type(4)));
typedef unsigned u32x4 __attribute__((ext_vector_type(4)));

#define B_ 64
#define S_ 512
#define E_ 512
#define H_ 1024
#define C_ 20
#define EH 1536   // E+H
#define G4 4096   // 4*H

// ---- workspace layout (bytes) ----
static const size_t OFF_WCAT  = 0;              // bf16 [4096][1536] = 12,582,912
static const size_t OFF_BIAS4 = 12582912;       // f32  [4096]       = 16,384
static const size_t OFF_AT0   = 12599296;       // u32x4 [64][256] tagged granules = 262,144
static const size_t OFF_AT1   = 12861440;       // u32x4 [64][256]   = 262,144
static const size_t OFF_CST   = 13123584;       // f32  [64][1024]   = 262,144
static const size_t OFF_LOSS  = 13385728;       // f32  [64]         = 256
static const size_t OFF_GX    = 13385984;       // bf16 [TC*64][4096] = TC*524,288
static const size_t STATE_BYTES = OFF_GX - OFF_AT0;   // 786,688 (zeroed each call)

__device__ inline float sigmoidf_(float x) { return 1.0f / (1.0f + __expf(-x)); }
__device__ inline float tanh_fast(float x) {
  float ax = fabsf(x);
  float e = __expf(-2.0f * ax);
  float t = (1.0f - e) / (1.0f + e);
  return copysignf(t, x);
}
__device__ inline float bf2f(unsigned lo16) {
  const unsigned u = lo16 << 16;
  return __builtin_bit_cast(float, u);
}

// ---- zero at0/at1/cst/loss (contiguous; resets tags every call) ----
__global__ __launch_bounds__(256) void init_misc(uint4* st) {
  const int n = (int)(STATE_BYTES / 16);   // 49,168
  for (int idx = blockIdx.x * 256 + threadIdx.x; idx < n; idx += gridDim.x * 256)
    st[idx] = uint4{0u, 0u, 0u, 0u};
}

// ---- convert gate weights to bf16, rows r = h*4+g (h-major, gate minor) ----
__global__ __launch_bounds__(256) void convert_w(
    const float* __restrict__ Wf, const float* __restrict__ Wi,
    const float* __restrict__ Wc, const float* __restrict__ Wo,
    const float* __restrict__ bfp, const float* __restrict__ bip,
    const float* __restrict__ bcp, const float* __restrict__ bop,
    bf16* __restrict__ Wcat, float* __restrict__ bias4)
{
  const int total = G4 * (EH / 8);   // 786,432 chunks of 8
  for (int idx = blockIdx.x * 256 + threadIdx.x; idx < total; idx += gridDim.x * 256) {
    const int r = idx / 192;
    const int ck = idx - r * 192;
    const int g = r & 3, h = r >> 2;
    const float* W = (g == 0) ? Wf : (g == 1) ? Wi : (g == 2) ? Wc : Wo;
    const float* src = W + (size_t)h * EH + ck * 8;
    const float4 v0 = *(const float4*)src;
    const float4 v1 = *(const float4*)(src + 4);
    bf16x8 o;
    o[0] = (bf16)v0.x; o[1] = (bf16)v0.y; o[2] = (bf16)v0.z; o[3] = (bf16)v0.w;
    o[4] = (bf16)v1.x; o[5] = (bf16)v1.y; o[6] = (bf16)v1.z; o[7] = (bf16)v1.w;
    *(bf16x8*)(Wcat + (size_t)r * EH + ck * 8) = o;
    if (ck == 0) {
      const float* Bp = (g == 0) ? bfp : (g == 1) ? bip : (g == 2) ? bcp : bop;
      bias4[r] = Bp[h];
    }
  }
}

// ---- gx_chunk[ml][r] = sum_k emb[x[m]][k] * Wcat[r][k], K = 512 (x-part) ----
__global__ __launch_bounds__(256) void gemm_gx(
    const int* __restrict__ x, const float* __restrict__ emb,
    const bf16* __restrict__ Wcat, bf16* __restrict__ gx, int t0)
{
  __shared__ char As[16384];
  __shared__ char Bs[16384];
  const int t = threadIdx.x;
  const int lane = t & 63, wid = t >> 6;
  const int wm = wid >> 1, wn = wid & 1;
  const int bm = blockIdx.x >> 5;
  const int bn = blockIdx.x & 31;
  const int m0l = bm * 128, n0 = bn * 128;
  f32x4 acc[4][4] = {};
  const int srow = t >> 3, sc16 = t & 7;
  for (int k0 = 0; k0 < E_; k0 += 64) {
    __syncthreads();
    #pragma unroll
    for (int i = 0; i < 4; ++i) {
      const int row = i * 32 + srow;
      const int cs = sc16 ^ (row & 7);     // pre-swizzled source chunk
      const int m = t0 * 64 + m0l + row;
      const int tok = x[(m & 63) * S_ + (m >> 6)];
      const float* srcA = emb + (size_t)tok * E_ + k0 + cs * 8;
      const float4 a0v = *(const float4*)srcA;
      const float4 a1v = *(const float4*)(srcA + 4);
      bf16x8 oa;
      oa[0] = (bf16)a0v.x; oa[1] = (bf16)a0v.y; oa[2] = (bf16)a0v.z; oa[3] = (bf16)a0v.w;
      oa[4] = (bf16)a1v.x; oa[5] = (bf16)a1v.y; oa[6] = (bf16)a1v.z; oa[7] = (bf16)a1v.w;
      *(bf16x8*)(As + row * 128 + sc16 * 16) = oa;
      const uint4 vb = *(const uint4*)(Wcat + (size_t)(n0 + row) * EH + k0 + cs * 8);
      *(uint4*)(Bs + row * 128 + sc16 * 16) = vb;
    }
    __syncthreads();
    #pragma unroll
    for (int ks = 0; ks < 64; ks += 32) {
      const int kb = (ks + ((lane >> 4) * 8)) * 2;
      bf16x8 af[4], bfr[4];
      #pragma unroll
      for (int mt = 0; mt < 4; ++mt) {
        const int ra = wm * 64 + mt * 16 + (lane & 15);
        af[mt] = *(const bf16x8*)(As + ra * 128 + (kb ^ ((ra & 7) << 4)));
      }
      #pragma unroll
      for (int nt = 0; nt < 4; ++nt) {
        const int rb = wn * 64 + nt * 16 + (lane & 15);
        bfr[nt] = *(const bf16x8*)(Bs + rb * 128 + (kb ^ ((rb & 7) << 4)));
      }
      #pragma unroll
      for (int mt = 0; mt < 4; ++mt)
        #pragma unroll
        for (int nt = 0; nt < 4; ++nt)
          acc[mt][nt] = __builtin_amdgcn_mfma_f32_16x16x32_bf16(af[mt], bfr[nt], acc[mt][nt], 0, 0, 0);
    }
  }
  const int cb = (lane >> 4) * 4;
  #pragma unroll
  for (int mt = 0; mt < 4; ++mt) {
    #pragma unroll
    for (int r = 0; r < 4; ++r) {
      const int mrow = m0l + wm * 64 + mt * 16 + cb + r;   // chunk-local row
      bf16* dst = gx + (size_t)mrow * G4 + n0 + wn * 64 + (lane & 15);
      #pragma unroll
      for (int nt = 0; nt < 4; ++nt)
        dst[nt * 16] = (bf16)acc[mt][nt][r];
    }
  }
}

// ---- persistent LSTM recurrence over steps [t0, t0+tc) ----
// 256 WGs = 4 batch-groups (16 batches) x 64 hidden-slice WGs (16 h each).
// R9 protocol = tagged granules (R6) + MASKED poll (the R6 fix):
//  * h published as 16B granules {4xbf16, tag=step+1, 0} via one sc0sc1
//    dwordx4 (tag travels atomically with data). No drain, no flags, no
//    post-publish barrier -- publish is the last op of the step.
//  * consumer polls its 16 granules; first iteration loads all 16 (that IS
//    the payload read); subsequent iterations reload ONLY stale ones
//    (need-mask). Detect+payload collapse into ~1 RTT when producer leads.
// Critical path/step: store-visible (1 RTT) + 1 poll iter (1 RTT) + compute.
// Depth-2 ring safety: tag s observed => that WG passed its reduce barrier
// for s-1 => its s-1 payload reads retired => overwriting s-1 slots is safe;
// consumer expecting tag s can only see s-2 (stale) or s, never s+2.
__global__ __launch_bounds__(256, 1) void lstm_rec(
    const bf16* __restrict__ Wcat, const float* __restrict__ bias4,
    const bf16* __restrict__ gx, unsigned* __restrict__ at0,
    unsigned* __restrict__ at1, float* __restrict__ cstg,
    int t0, int tc)
{
  __shared__ __align__(16) float accs[2][4][16][68];   // parity double-buffer
  const int t = threadIdx.x;
  const int lane = t & 63;
  const int w = t >> 6;                     // wave id = K-quarter
  const int bid = blockIdx.x;
  const int grp = bid & 3;                  // batch group (16 batches)
  const int hwg = bid >> 2;                 // 0..63 hidden slice
  const int h0 = hwg * 16;
  const int l15 = lane & 15;
  const int ksub = lane >> 4;               // 0..3
  const int kq8 = ksub * 8;

  // --- preload W B-fragments: 64 gate rows x my K-quarter (256 cols) ---
  bf16x8 wf[32];                            // static-indexed -> regs/AGPRs
  {
    const bf16* wbase = Wcat + (size_t)(h0 * 4 + l15) * EH + 512 + w * 256 + kq8;
    #pragma unroll
    for (int nt = 0; nt < 4; ++nt)
      #pragma unroll
      for (int i = 0; i < 8; ++i)
        wf[nt * 8 + i] = *(const bf16x8*)(wbase + (size_t)nt * 16 * EH + i * 32);
  }
  const int j   = t & 15;                   // hidden unit within slice
  const int blb = t >> 4;                   // batch within group
  const float4 bias = *(const float4*)(bias4 + (h0 + j) * 4);
  const int bg0 = grp * 16 + blb;
  float cst = cstg[(size_t)bg0 * H_ + h0 + j];
  // consumer granule base (dwords): batch grp*16+l15, first granule w*64+ksub*2
  const size_t aboff = ((size_t)(grp * 16 + l15) * 256 + (size_t)(w * 64 + ksub * 2)) * 4;
  // producer granule (dwords): [bg0][hwg*4 + (j>>2)], stored by j%4==0 lanes
  const size_t pgoff = ((size_t)bg0 * 256 + (size_t)(hwg * 4 + (j >> 2))) * 4;

  for (int s = 0; s < tc; ++s) {
    const int step = t0 + s;
    const unsigned exp_tag = (unsigned)step;        // tag of h(step-1)
    const unsigned* aprev = (step & 1) ? at1 : at0; // buffer step&1 holds h(step-1)
    unsigned* anext = (step & 1) ? at0 : at1;
    // gx for this step (plain cached load; completes under first poll vmcnt)
    const bf16x4 g0 = *(const bf16x4*)(gx + (size_t)s * (B_ * G4) + (size_t)bg0 * G4 + (h0 + j) * 4);

    // ---- masked tagged poll: granule q (q=2i+half) at +(i*8+half)*4 dwords ----
    const unsigned* abase = aprev + aboff;
    u32x4 g[16];
    unsigned need = 0xFFFFu;
    for (;;) {
      #pragma unroll
      for (int q = 0; q < 16; ++q) {
        if (need & (1u << q)) {
          const int dw = ((q >> 1) * 8 + (q & 1)) * 4;
          asm volatile("global_load_dwordx4 %0, %1, off sc0 sc1"
                       : "=v"(g[q]) : "v"(abase + dw) : "memory");
        }
      }
      asm volatile("s_waitcnt vmcnt(0)" ::: "memory");
      __builtin_amdgcn_sched_barrier(0);
      unsigned nn = 0u;
      #pragma unroll
      for (int q = 0; q < 16; ++q)
        if ((need & (1u << q)) && (g[q].z != exp_tag)) nn |= (1u << q);
      need = nn;
      if (__all(need == 0u)) break;
    }
    __builtin_amdgcn_sched_barrier(0);

    // ---- MFMA over my K-quarter ----
    f32x4 pacc[4] = {};
    #pragma unroll
    for (int i = 0; i < 8; ++i) {
      u32x4 mg;
      mg.x = g[2 * i].x; mg.y = g[2 * i].y;
      mg.z = g[2 * i + 1].x; mg.w = g[2 * i + 1].y;
      const bf16x8 a8 = __builtin_bit_cast(bf16x8, mg);
      #pragma unroll
      for (int nt = 0; nt < 4; ++nt)
        pacc[nt] = __builtin_amdgcn_mfma_f32_16x16x32_bf16(a8, wf[nt * 8 + i], pacc[nt], 0, 0, 0);
    }
    // ---- cross-wave K-reduction via parity LDS (single barrier) ----
    const int par = step & 1;
    {
      const int m0 = ksub * 4;
      #pragma unroll
      for (int nt = 0; nt < 4; ++nt)
        #pragma unroll
        for (int r = 0; r < 4; ++r)
          accs[par][w][m0 + r][nt * 16 + l15] = pacc[nt][r];
    }
    __syncthreads();
    const float4 q0 = *(const float4*)&accs[par][0][blb][j * 4];
    const float4 q1 = *(const float4*)&accs[par][1][blb][j * 4];
    const float4 q2 = *(const float4*)&accs[par][2][blb][j * 4];
    const float4 q3 = *(const float4*)&accs[par][3][blb][j * 4];
    float hv;
    {
      const float pf = q0.x + q1.x + q2.x + q3.x + (float)g0[0] + bias.x;
      const float pi = q0.y + q1.y + q2.y + q3.y + (float)g0[1] + bias.y;
      const float pc = q0.z + q1.z + q2.z + q3.z + (float)g0[2] + bias.z;
      const float po = q0.w + q1.w + q2.w + q3.w + (float)g0[3] + bias.w;
      const float fg = sigmoidf_(pf), ig = sigmoidf_(pi), og = sigmoidf_(po);
      cst = fg * cst + ig * tanh_fast(pc);
      hv = tanh_fast(cst) * og;
    }
    // ---- tagged publish: one 16B sc0sc1 store per 4 h-units; no drain ----
    {
      const unsigned me  = (unsigned)__builtin_bit_cast(unsigned short, (bf16)hv);
      const unsigned pr  = me | (__shfl_down(me, 1) << 16);
      const unsigned pr2 = __shfl_down(pr, 2);
      if ((j & 3) == 0) {
        u32x4 o; o.x = pr; o.y = pr2; o.z = (unsigned)(step + 1); o.w = 0u;
        asm volatile("global_store_dwordx4 %0, %1, off sc0 sc1"
                     :: "v"(anext + pgoff), "v"(o) : "memory");
      }
    }
  }
  cstg[(size_t)bg0 * H_ + h0 + j] = cst;
}

// ---- logits + per-batch loss (reads tagged final state, strips tags) ----
__global__ __launch_bounds__(256) void logits_loss(
    const unsigned* __restrict__ at, const float* __restrict__ Wv,
    const float* __restrict__ bv, const int* __restrict__ label,
    float* __restrict__ lossa)
{
  const int b = blockIdx.x;
  const int t = threadIdx.x;
  const int lane = t & 63, wid = t >> 6;
  const u32x4 gv = *(const u32x4*)(at + ((size_t)b * 256 + t) * 4);
  const float av0 = bf2f(gv.x & 0xffffu), av1 = bf2f(gv.x >> 16);
  const float av2 = bf2f(gv.y & 0xffffu), av3 = bf2f(gv.y >> 16);
  float part[C_];
  #pragma unroll
  for (int c = 0; c < C_; ++c) {
    const float4 w = *(const float4*)(Wv + (size_t)c * H_ + t * 4);
    part[c] = av0 * w.x + av1 * w.y + av2 * w.z + av3 * w.w;
  }
  #pragma unroll
  for (int off = 32; off > 0; off >>= 1) {
    #pragma unroll
    for (int c = 0; c < C_; ++c) part[c] += __shfl_down(part[c], off);
  }
  __shared__ float red[4][C_];
  __shared__ float lg[C_];
  if (lane == 0) {
    #pragma unroll
    for (int c = 0; c < C_; ++c) red[wid][c] = part[c];
  }
  __syncthreads();
  if (t < C_) lg[t] = red[0][t] + red[1][t] + red[2][t] + red[3][t] + bv[t];
  __syncthreads();
  if (t == 0) {
    float m = lg[0];
    for (int c = 1; c < C_; ++c) m = fmaxf(m, lg[c]);
    float se = 0.0f;
    for (int c = 0; c < C_; ++c) se += __expf(lg[c] - m);
    const float lse = logf(se) + m;
    lossa[b] = lse - lg[label[b]];
  }
}

__global__ __launch_bounds__(64) void loss_mean(const float* __restrict__ lossa,
                                                float* __restrict__ out) {
  const int t = threadIdx.x;
  float v = lossa[t];
  #pragma unroll
  for (int off = 32; off > 0; off >>= 1) v += __shfl_down(v, off);
  if (t == 0) out[0] = v * (1.0f / 64.0f);
}

extern "C" void kernel_launch(void* const* d_in, const int* in_sizes, int n_in,
                              void* d_out, int out_size, void* d_ws, size_t ws_size,
                              hipStream_t stream) {
  const int*   x     = (const int*)d_in[0];
  const int*   label = (const int*)d_in[1];
  const float* emb   = (const float*)d_in[2];
  const float* Wf    = (const float*)d_in[3];
  const float* bfp   = (const float*)d_in[4];
  const float* Wi    = (const float*)d_in[5];
  const float* bip   = (const float*)d_in[6];
  const float* Wc    = (const float*)d_in[7];
  const float* bcp   = (const float*)d_in[8];
  const float* Wo    = (const float*)d_in[9];
  const float* bop   = (const float*)d_in[10];
  const float* Wv    = (const float*)d_in[11];
  const float* bv    = (const float*)d_in[12];
  (void)in_sizes; (void)n_in; (void)out_size;

  // Pick the largest time-chunk TC whose gx buffer fits the workspace.
  int TC = 0;
  const size_t avail = (ws_size > OFF_GX) ? (ws_size - OFF_GX) : 0;
  const int cands[7] = {512, 256, 128, 64, 32, 16, 8};
  for (int i = 0; i < 7; ++i) {
    if ((size_t)cands[i] * 524288 <= avail) { TC = cands[i]; break; }
  }
  if (TC == 0) return;   // ws < ~17.9 MB — cannot run this design

  char* ws = (char*)d_ws;
  bf16*     Wcat  = (bf16*)(ws + OFF_WCAT);
  float*    bias4 = (float*)(ws + OFF_BIAS4);
  unsigned* at0   = (unsigned*)(ws + OFF_AT0);
  unsigned* at1   = (unsigned*)(ws + OFF_AT1);
  float*    cstg  = (float*)(ws + OFF_CST);
  float*    lossa = (float*)(ws + OFF_LOSS);
  bf16*     gx    = (bf16*)(ws + OFF_GX);

  init_misc<<<64, 256, 0, stream>>>((uint4*)(ws + OFF_AT0));
  convert_w<<<1024, 256, 0, stream>>>(Wf, Wi, Wc, Wo, bfp, bip, bcp, bop, Wcat, bias4);
  const int nchunks = S_ / TC;
  for (int c = 0; c < nchunks; ++c) {
    const int t0 = c * TC;
    gemm_gx<<<(TC / 2) * 32, 256, 0, stream>>>(x, emb, Wcat, gx, t0);
    lstm_rec<<<256, 256, 0, stream>>>(Wcat, bias4, gx, at0, at1, cstg, t0, TC);
  }
  // final state = h(511), buffer (511+1)&1 = 0 -> at0
  logits_loss<<<64, 256, 0, stream>>>(at0, Wv, bv, label, lossa);
  loss_mean<<<1, 64, 0, stream>>>(lossa, (float*)d_out);
}

// Round 11
// 2540.914 us; speedup vs baseline: 1.2143x; 1.0005x over previous
//
#include <hip/hip_runtime.h>
#include <cstdint>
#include <cstddef>

typedef __bf16 bf16;
typedef __bf16 bf16x8 __attribute__((ext_vector_type(8)));
typedef __bf16 bf16x4 __attribute__((ext_vector_type(4)));
typedef float f32x4 __attribute__((ext_vector_type(4)));
typedef unsigned u32x4 __attribute__((ext_vector_type(4)));

#define B_ 64
#define S_ 512
#define E_ 512
#define H_ 1024
#define C_ 20
#define EH 1536   // E+H
#define G4 4096   // 4*H
#define NROLE 32  // WGs per XCD-group
#define GRP_B 8   // batches per XCD-group

// ---- workspace layout (bytes) ----
static const size_t OFF_WCAT  = 0;              // bf16 [4096][1536] = 12,582,912
static const size_t OFF_BIAS4 = 12582912;       // f32  [4096]       = 16,384
static const size_t OFF_H0    = 12599296;       // bf16 [64][1024]   = 131,072
static const size_t OFF_H1    = 12730368;       // bf16 [64][1024]   = 131,072
static const size_t OFF_CST   = 12861440;       // f32  [64][1024]   = 262,144
static const size_t OFF_LOSS  = 13123584;       // f32  [64]         = 256
static const size_t OFF_FLG   = 13123840;       // u32  [8][32] role flags = 1,024
static const size_t OFF_CNT   = 13124864;       // u32  [64 chunks][8] = 2,048
static const size_t OFF_GX    = 13126912;       // bf16 [TC*64][4096] = TC*524,288
static const size_t STATE_BYTES = OFF_GX - OFF_H0;   // 527,616 (zeroed each call)

__device__ inline float sigmoidf_(float x) { return 1.0f / (1.0f + __expf(-x)); }
__device__ inline float tanh_fast(float x) {
  float ax = fabsf(x);
  float e = __expf(-2.0f * ax);
  float t = (1.0f - e) / (1.0f + e);
  return copysignf(t, x);
}

// ---- zero h0/h1/cst/loss/flags/cnt (contiguous state region) ----
__global__ __launch_bounds__(256) void init_misc(uint4* st) {
  const int n = (int)(STATE_BYTES / 16);   // 32,976
  for (int idx = blockIdx.x * 256 + threadIdx.x; idx < n; idx += gridDim.x * 256)
    st[idx] = uint4{0u, 0u, 0u, 0u};
}

// ---- convert gate weights to bf16, rows r = h*4+g (h-major, gate minor) ----
__global__ __launch_bounds__(256) void convert_w(
    const float* __restrict__ Wf, const float* __restrict__ Wi,
    const float* __restrict__ Wc, const float* __restrict__ Wo,
    const float* __restrict__ bfp, const float* __restrict__ bip,
    const float* __restrict__ bcp, const float* __restrict__ bop,
    bf16* __restrict__ Wcat, float* __restrict__ bias4)
{
  const int total = G4 * (EH / 8);   // 786,432 chunks of 8
  for (int idx = blockIdx.x * 256 + threadIdx.x; idx < total; idx += gridDim.x * 256) {
    const int r = idx / 192;
    const int ck = idx - r * 192;
    const int g = r & 3, h = r >> 2;
    const float* W = (g == 0) ? Wf : (g == 1) ? Wi : (g == 2) ? Wc : Wo;
    const float* src = W + (size_t)h * EH + ck * 8;
    const float4 v0 = *(const float4*)src;
    const float4 v1 = *(const float4*)(src + 4);
    bf16x8 o;
    o[0] = (bf16)v0.x; o[1] = (bf16)v0.y; o[2] = (bf16)v0.z; o[3] = (bf16)v0.w;
    o[4] = (bf16)v1.x; o[5] = (bf16)v1.y; o[6] = (bf16)v1.z; o[7] = (bf16)v1.w;
    *(bf16x8*)(Wcat + (size_t)r * EH + ck * 8) = o;
    if (ck == 0) {
      const float* Bp = (g == 0) ? bfp : (g == 1) ? bip : (g == 2) ? bcp : bop;
      bias4[r] = Bp[h];
    }
  }
}

// ---- gx_chunk[ml][r] = sum_k emb[x[m]][k] * Wcat[r][k], K = 512 (x-part) ----
__global__ __launch_bounds__(256) void gemm_gx(
    const int* __restrict__ x, const float* __restrict__ emb,
    const bf16* __restrict__ Wcat, bf16* __restrict__ gx, int t0)
{
  __shared__ char As[16384];
  __shared__ char Bs[16384];
  const int t = threadIdx.x;
  const int lane = t & 63, wid = t >> 6;
  const int wm = wid >> 1, wn = wid & 1;
  const int bm = blockIdx.x >> 5;
  const int bn = blockIdx.x & 31;
  const int m0l = bm * 128, n0 = bn * 128;
  f32x4 acc[4][4] = {};
  const int srow = t >> 3, sc16 = t & 7;
  for (int k0 = 0; k0 < E_; k0 += 64) {
    __syncthreads();
    #pragma unroll
    for (int i = 0; i < 4; ++i) {
      const int row = i * 32 + srow;
      const int cs = sc16 ^ (row & 7);     // pre-swizzled source chunk
      const int m = t0 * 64 + m0l + row;
      const int tok = x[(m & 63) * S_ + (m >> 6)];
      const float* srcA = emb + (size_t)tok * E_ + k0 + cs * 8;
      const float4 a0v = *(const float4*)srcA;
      const float4 a1v = *(const float4*)(srcA + 4);
      bf16x8 oa;
      oa[0] = (bf16)a0v.x; oa[1] = (bf16)a0v.y; oa[2] = (bf16)a0v.z; oa[3] = (bf16)a0v.w;
      oa[4] = (bf16)a1v.x; oa[5] = (bf16)a1v.y; oa[6] = (bf16)a1v.z; oa[7] = (bf16)a1v.w;
      *(bf16x8*)(As + row * 128 + sc16 * 16) = oa;
      const uint4 vb = *(const uint4*)(Wcat + (size_t)(n0 + row) * EH + k0 + cs * 8);
      *(uint4*)(Bs + row * 128 + sc16 * 16) = vb;
    }
    __syncthreads();
    #pragma unroll
    for (int ks = 0; ks < 64; ks += 32) {
      const int kb = (ks + ((lane >> 4) * 8)) * 2;
      bf16x8 af[4], bfr[4];
      #pragma unroll
      for (int mt = 0; mt < 4; ++mt) {
        const int ra = wm * 64 + mt * 16 + (lane & 15);
        af[mt] = *(const bf16x8*)(As + ra * 128 + (kb ^ ((ra & 7) << 4)));
      }
      #pragma unroll
      for (int nt = 0; nt < 4; ++nt) {
        const int rb = wn * 64 + nt * 16 + (lane & 15);
        bfr[nt] = *(const bf16x8*)(Bs + rb * 128 + (kb ^ ((rb & 7) << 4)));
      }
      #pragma unroll
      for (int mt = 0; mt < 4; ++mt)
        #pragma unroll
        for (int nt = 0; nt < 4; ++nt)
          acc[mt][nt] = __builtin_amdgcn_mfma_f32_16x16x32_bf16(af[mt], bfr[nt], acc[mt][nt], 0, 0, 0);
    }
  }
  const int cb = (lane >> 4) * 4;
  #pragma unroll
  for (int mt = 0; mt < 4; ++mt) {
    #pragma unroll
    for (int r = 0; r < 4; ++r) {
      const int mrow = m0l + wm * 64 + mt * 16 + cb + r;   // chunk-local row
      bf16* dst = gx + (size_t)mrow * G4 + n0 + wn * 64 + (lane & 15);
      #pragma unroll
      for (int nt = 0; nt < 4; ++nt)
        dst[nt * 16] = (bf16)acc[mt][nt][r];
    }
  }
}

// ---- persistent LSTM recurrence over steps [t0, t0+tc), XCD-local payload ----
// R11 = R10 structure with scope-split protocol (deadlock-proof bisection):
//  * FLAGS via MALL (sc0 sc1) — exactly the R5-proven path; progress can
//    never depend on XCD grouping, so this kernel cannot deadlock.
//  * PAYLOAD via XCD-local L2 (sc0 publish + wave drain before barrier;
//    sc0 read-once after flag). Flag(MALL) >= s implies producer's L2
//    stores drained, so a same-XCD consumer reads fresh L2 data.
//  * XCC_ID masked &7 (OOB-poll hang class removed).
// If XCD grouping were impure, result = wrong data (absmax flags it), not
// a hang — diagnostic either way.
__global__ __launch_bounds__(512, 2) void lstm_rec(
    const bf16* __restrict__ Wcat, const float* __restrict__ bias4,
    const bf16* __restrict__ gx, bf16* __restrict__ hb0,
    bf16* __restrict__ hb1, float* __restrict__ cstg,
    unsigned* __restrict__ flags, unsigned* __restrict__ cnt,
    int t0, int tc, int chunk)
{
  __shared__ __align__(16) float accs[8][8][132];
  __shared__ int role_s, xcd_s;
  const int tid = threadIdx.x;
  if (tid == 0) {
    unsigned xr;
    asm volatile("s_getreg_b32 %0, hwreg(HW_REG_XCC_ID)" : "=s"(xr));
    xr &= 7u;
    xcd_s = (int)xr;
    role_s = (int)atomicAdd(&cnt[chunk * 8 + (int)xr], 1u);
  }
  __syncthreads();
  const int role = role_s;
  const int xcd  = xcd_s;
  if (role >= NROLE) return;    // surplus WG: exit immediately

  const int lane = tid & 63;
  const int w = tid >> 6;            // wave id = K-eighth [w*128, w*128+128)
  const int l15 = lane & 15;
  const int ksub = lane >> 4;        // 0..3
  const int kq8 = ksub * 8;

  // --- preload W B-fragments: 128 gate rows x my K-eighth (128 cols) ---
  bf16x8 wf[32];                     // [nt*4 + kc], static-indexed
  {
    const bf16* wb = Wcat + (size_t)(role * 128 + l15) * EH + 512 + w * 128 + kq8;
    #pragma unroll
    for (int nt = 0; nt < 8; ++nt)
      #pragma unroll
      for (int kc = 0; kc < 4; ++kc)
        wf[nt * 4 + kc] = *(const bf16x8*)(wb + (size_t)nt * 16 * EH + kc * 32);
  }
  // item mapping (tid < 256): b-local = tid>>5 (0..7), h-local = tid&31
  const int ib = tid >> 5;
  const int hl = tid & 31;
  const int gb = xcd * GRP_B + ib;   // global batch for this item
  float4 bias = {0.f, 0.f, 0.f, 0.f};
  float cst = 0.f;
  if (tid < 256) {
    bias = *(const float4*)(bias4 + (role * 32 + hl) * 4);
    cst = cstg[(size_t)gb * H_ + role * 32 + hl];
  }
  // consumer payload base: batch xcd*8+(l15&7), cols w*128 + kc*32 + kq8
  const size_t pbase = (size_t)(xcd * GRP_B + (l15 & 7)) * H_ + w * 128 + kq8;
  const unsigned* fp = flags + xcd * 32 + w * 4;   // my 4 producers' flags
  unsigned* const myflag = flags + xcd * 32 + role;
  bf16* const pub0 = hb0 + (size_t)gb * H_ + role * 32 + hl;
  bf16* const pub1 = hb1 + (size_t)gb * H_ + role * 32 + hl;

  for (int s = 0; s < tc; ++s) {
    const int step = t0 + s;
    const bf16* hprev = (step & 1) ? hb0 : hb1;   // h(step-1) in buf[(step-1)&1]
    // gx prefetch (plain cached; drains under the poll's vmcnt)
    bf16x4 g0 = {};
    if (tid < 256)
      g0 = *(const bf16x4*)(gx + (size_t)s * (B_ * G4) + (size_t)gb * G4 + (role * 32 + hl) * 4);

    // ---- poll my 4 producer flags at MALL scope (proven R5 path) ----
    {
      const unsigned tgt = (unsigned)step;
      u32x4 fq;
      for (;;) {
        asm volatile("global_load_dwordx4 %0, %1, off sc0 sc1"
                     : "=v"(fq) : "v"(fp) : "memory");
        asm volatile("s_waitcnt vmcnt(0)" ::: "memory");
        __builtin_amdgcn_sched_barrier(0);
        if (fq.x >= tgt && fq.y >= tgt && fq.z >= tgt && fq.w >= tgt) break;
      }
    }
    __builtin_amdgcn_sched_barrier(0);
    // ---- payload: 4 x 16B sc0 loads (XCD-local L2), read exactly once ----
    u32x4 pay[4];
    #pragma unroll
    for (int kc = 0; kc < 4; ++kc)
      asm volatile("global_load_dwordx4 %0, %1, off sc0"
                   : "=v"(pay[kc]) : "v"(hprev + pbase + kc * 32) : "memory");
    asm volatile("s_waitcnt vmcnt(0)" ::: "memory");
    __builtin_amdgcn_sched_barrier(0);

    // ---- MFMA over my K-eighth: 4 k-chunks x 8 n-tiles ----
    f32x4 pacc[8] = {};
    #pragma unroll
    for (int kc = 0; kc < 4; ++kc) {
      const bf16x8 a8 = __builtin_bit_cast(bf16x8, pay[kc]);
      #pragma unroll
      for (int nt = 0; nt < 8; ++nt)
        pacc[nt] = __builtin_amdgcn_mfma_f32_16x16x32_bf16(a8, wf[nt * 4 + kc], pacc[nt], 0, 0, 0);
    }
    // ---- partial store (batch rows 0..7 only) ----
    if (ksub < 2) {
      #pragma unroll
      for (int nt = 0; nt < 8; ++nt)
        #pragma unroll
        for (int r = 0; r < 4; ++r)
          accs[w][ksub * 4 + r][nt * 16 + l15] = pacc[nt][r];
    }
    __syncthreads();
    // ---- item phase: reduce 8 K-partials, gates, publish (L2 scope) ----
    if (tid < 256) {
      float s0 = 0.f, s1 = 0.f, s2 = 0.f, s3 = 0.f;
      #pragma unroll
      for (int ww = 0; ww < 8; ++ww) {
        const float4 q = *(const float4*)&accs[ww][ib][hl * 4];
        s0 += q.x; s1 += q.y; s2 += q.z; s3 += q.w;
      }
      const float pf = s0 + (float)g0[0] + bias.x;
      const float pi = s1 + (float)g0[1] + bias.y;
      const float pc = s2 + (float)g0[2] + bias.z;
      const float po = s3 + (float)g0[3] + bias.w;
      const float fg = sigmoidf_(pf), ig = sigmoidf_(pi), og = sigmoidf_(po);
      cst = fg * cst + ig * tanh_fast(pc);
      const float hv = tanh_fast(cst) * og;
      // oct-pack 8 h-values -> one 16B sc0 store per 8 items
      const unsigned me  = (unsigned)__builtin_bit_cast(unsigned short, (bf16)hv);
      const unsigned pr  = me | (__shfl_down(me, 1) << 16);
      const unsigned pr2 = __shfl_down(pr, 2);
      const unsigned pr4 = __shfl_down(pr, 4);
      const unsigned pr24 = __shfl_down(pr2, 4);
      if ((hl & 7) == 0) {
        u32x4 o; o.x = pr; o.y = pr2; o.z = pr4; o.w = pr24;
        bf16* dst = (step & 1) ? pub1 : pub0;   // h(step) -> buf[step&1]
        asm volatile("global_store_dwordx4 %0, %1, off sc0"
                     :: "v"(dst), "v"(o) : "memory");
      }
      asm volatile("s_waitcnt vmcnt(0)" ::: "memory");   // wave-local drain
    }
    __syncthreads();
    if (tid == 0) {
      const unsigned nf = (unsigned)(step + 1);
      asm volatile("global_store_dword %0, %1, off sc0 sc1"
                   :: "v"(myflag), "v"(nf) : "memory");
    }
    __builtin_amdgcn_sched_barrier(0);
  }
  if (tid < 256) cstg[(size_t)gb * H_ + role * 32 + hl] = cst;
}

// ---- logits + per-batch loss ----
__global__ __launch_bounds__(256) void logits_loss(
    const bf16* __restrict__ afin, const float* __restrict__ Wv,
    const float* __restrict__ bv, const int* __restrict__ label,
    float* __restrict__ lossa)
{
  const int b = blockIdx.x;
  const int t = threadIdx.x;
  const int lane = t & 63, wid = t >> 6;
  const bf16x4 a4 = *(const bf16x4*)(afin + (size_t)b * H_ + t * 4);
  const float av0 = (float)a4[0], av1 = (float)a4[1], av2 = (float)a4[2], av3 = (float)a4[3];
  float part[C_];
  #pragma unroll
  for (int c = 0; c < C_; ++c) {
    const float4 w = *(const float4*)(Wv + (size_t)c * H_ + t * 4);
    part[c] = av0 * w.x + av1 * w.y + av2 * w.z + av3 * w.w;
  }
  #pragma unroll
  for (int off = 32; off > 0; off >>= 1) {
    #pragma unroll
    for (int c = 0; c < C_; ++c) part[c] += __shfl_down(part[c], off);
  }
  __shared__ float red[4][C_];
  __shared__ float lg[C_];
  if (lane == 0) {
    #pragma unroll
    for (int c = 0; c < C_; ++c) red[wid][c] = part[c];
  }
  __syncthreads();
  if (t < C_) lg[t] = red[0][t] + red[1][t] + red[2][t] + red[3][t] + bv[t];
  __syncthreads();
  if (t == 0) {
    float m = lg[0];
    for (int c = 1; c < C_; ++c) m = fmaxf(m, lg[c]);
    float se = 0.0f;
    for (int c = 0; c < C_; ++c) se += __expf(lg[c] - m);
    const float lse = logf(se) + m;
    lossa[b] = lse - lg[label[b]];
  }
}

__global__ __launch_bounds__(64) void loss_mean(const float* __restrict__ lossa,
                                                float* __restrict__ out) {
  const int t = threadIdx.x;
  float v = lossa[t];
  #pragma unroll
  for (int off = 32; off > 0; off >>= 1) v += __shfl_down(v, off);
  if (t == 0) out[0] = v * (1.0f / 64.0f);
}

extern "C" void kernel_launch(void* const* d_in, const int* in_sizes, int n_in,
                              void* d_out, int out_size, void* d_ws, size_t ws_size,
                              hipStream_t stream) {
  const int*   x     = (const int*)d_in[0];
  const int*   label = (const int*)d_in[1];
  const float* emb   = (const float*)d_in[2];
  const float* Wf    = (const float*)d_in[3];
  const float* bfp   = (const float*)d_in[4];
  const float* Wi    = (const float*)d_in[5];
  const float* bip   = (const float*)d_in[6];
  const float* Wc    = (const float*)d_in[7];
  const float* bcp   = (const float*)d_in[8];
  const float* Wo    = (const float*)d_in[9];
  const float* bop   = (const float*)d_in[10];
  const float* Wv    = (const float*)d_in[11];
  const float* bv    = (const float*)d_in[12];
  (void)in_sizes; (void)n_in; (void)out_size;

  // Pick the largest time-chunk TC whose gx buffer fits the workspace.
  int TC = 0;
  const size_t avail = (ws_size > OFF_GX) ? (ws_size - OFF_GX) : 0;
  const int cands[7] = {512, 256, 128, 64, 32, 16, 8};
  for (int i = 0; i < 7; ++i) {
    if ((size_t)cands[i] * 524288 <= avail) { TC = cands[i]; break; }
  }
  if (TC == 0) return;   // ws < ~17.6 MB — cannot run this design

  char* ws = (char*)d_ws;
  bf16*     Wcat  = (bf16*)(ws + OFF_WCAT);
  float*    bias4 = (float*)(ws + OFF_BIAS4);
  bf16*     hb0   = (bf16*)(ws + OFF_H0);
  bf16*     hb1   = (bf16*)(ws + OFF_H1);
  float*    cstg  = (float*)(ws + OFF_CST);
  float*    lossa = (float*)(ws + OFF_LOSS);
  unsigned* flags = (unsigned*)(ws + OFF_FLG);
  unsigned* cnt   = (unsigned*)(ws + OFF_CNT);
  bf16*     gx    = (bf16*)(ws + OFF_GX);

  init_misc<<<64, 256, 0, stream>>>((uint4*)(ws + OFF_H0));
  convert_w<<<1024, 256, 0, stream>>>(Wf, Wi, Wc, Wo, bfp, bip, bcp, bop, Wcat, bias4);
  const int nchunks = S_ / TC;
  for (int c = 0; c < nchunks; ++c) {
    const int t0 = c * TC;
    gemm_gx<<<(TC / 2) * 32, 256, 0, stream>>>(x, emb, Wcat, gx, t0);
    lstm_rec<<<512, 512, 0, stream>>>(Wcat, bias4, gx, hb0, hb1, cstg, flags, cnt, t0, TC, c);
  }
  // final state = h(511) in buf[511&1] = hb1
  logits_loss<<<64, 256, 0, stream>>>(hb1, Wv, bv, label, lossa);
  loss_mean<<<1, 64, 0, stream>>>(lossa, (float*)d_out);
}